// Round 7
// baseline (375.879 us; speedup 1.0000x reference)
//
#include <hip/hip_runtime.h>

#define BDIM 16384
#define IN_D 151
#define HID_D 200
#define CENT_D 2000

// padded dims
#define INP 192     // K of GEMM0
#define HIDP 256    // N of GEMM0, K of GEMM1
#define CENTP 2048  // N of GEMM1/2, K of GEMM2/3
#define KERNR 256   // padded rows for kern/centres

using bf16x8 = __attribute__((ext_vector_type(8))) short;
using f32x4  = __attribute__((ext_vector_type(4))) float;
using f4     = __attribute__((ext_vector_type(4))) float;
using us4    = __attribute__((ext_vector_type(4))) unsigned short;
using us8    = __attribute__((ext_vector_type(8))) unsigned short;
using i32x4  = __attribute__((ext_vector_type(4))) int;
using i32x8  = __attribute__((ext_vector_type(8))) int;

__device__ __forceinline__ unsigned short f2bf(float f) {
  unsigned u = __builtin_bit_cast(unsigned, f);
  u += 0x7FFFu + ((u >> 16) & 1u);
  return (unsigned short)(u >> 16);
}
__device__ __forceinline__ float bf2f(unsigned short h) {
  unsigned u = ((unsigned)h) << 16;
  return __builtin_bit_cast(float, u);
}
__device__ __forceinline__ unsigned char f2fp8(float f) {
  return (unsigned char)(__builtin_amdgcn_cvt_pk_fp8_f32(f, f, 0, false) & 0xFF);
}
// fp8 e4m3fn decode (no exotic builtins; h >= 0 and finite here)
__device__ __forceinline__ float fp8d(unsigned b) {
  unsigned s = b >> 7, e = (b >> 3) & 15, m = b & 7;
  unsigned fb = (s << 31) | ((e + 120) << 23) | (m << 20);
  float nrm = __builtin_bit_cast(float, fb);
  float sub = (s ? -1.f : 1.f) * (float)m * 0.001953125f;  // m * 2^-9
  return e ? nrm : sub;
}
// fp4 e2m1 levels: 0, .5, 1, 1.5, 2, 3, 4, 6 (+sign in bit 3)
__device__ __forceinline__ unsigned f2fp4(float f) {
  float a = fabsf(f);
  unsigned s = (__builtin_bit_cast(unsigned, f) >> 31) << 3;
  unsigned m;
  if      (a < 0.25f) m = 0;
  else if (a < 0.75f) m = 1;
  else if (a < 1.25f) m = 2;
  else if (a < 1.75f) m = 3;
  else if (a < 2.5f)  m = 4;
  else if (a < 3.5f)  m = 5;
  else if (a < 5.0f)  m = 6;
  else                m = 7;
  return s | m;
}

typedef __attribute__((address_space(1))) const unsigned int guint;
typedef __attribute__((address_space(3))) unsigned int luint;
__device__ __forceinline__ void g2l16(const void* g, void* l) {
  __builtin_amdgcn_global_load_lds((guint*)g, (luint*)l, 16, 0, 0);
}

struct GArgs {
  const unsigned short* A;   // M x K bf16 row-major
  const unsigned short* B;   // N x K bf16 row-major
  int K;
  int kspan;                 // K-range per blockIdx.z
  const float* x2; const float* c2; const float* sg2;  // MODE 0
  const float* bias;                                    // MODE 1
  unsigned short* obf; int ldo;                         // MODE 0
  unsigned char* o8;                                    // MODE 1 (fp8 h)
  float* of;                                            // MODE 3 (per-z slab)
};

// ---------------------------------------------------------------------------
// bf16 128x128 tile, BK=64, 4 waves, 2-barrier structure (GEMM0/1/3).
// ---------------------------------------------------------------------------
template<int MODE>
__global__ __launch_bounds__(256) void gemm_bt(GArgs p) {
  __shared__ __align__(16) short As[128 * 64];
  __shared__ __align__(16) short Bs[128 * 64];
  const int tid  = threadIdx.x;
  const int lane = tid & 63;
  const int w    = tid >> 6;
  const int wr   = w >> 1, wc = w & 1;
  const int lr   = lane & 15;
  const int tm = blockIdx.x, tn = blockIdx.y;
  const int K = p.K;
  const int kbeg = blockIdx.z * p.kspan;
  f32x4 acc[4][4] = {};

  const unsigned short* Ag = p.A + (size_t)tm * 128 * K;
  const unsigned short* Bg = p.B + (size_t)tn * 128 * K;

  int rowc[4], colc[4], ldsc[4];
#pragma unroll
  for (int i = 0; i < 4; i++) {
    int cc = i * 256 + tid;
    rowc[i] = cc >> 3;
    colc[i] = ((cc & 7) ^ (rowc[i] & 7)) * 8;
    ldsc[i] = cc * 8;
  }

  for (int k0 = kbeg; k0 < kbeg + p.kspan; k0 += 64) {
    __syncthreads();
#pragma unroll
    for (int i = 0; i < 4; i++)
      g2l16(Ag + (size_t)rowc[i] * K + k0 + colc[i], &As[ldsc[i]]);
#pragma unroll
    for (int i = 0; i < 4; i++)
      g2l16(Bg + (size_t)rowc[i] * K + k0 + colc[i], &Bs[ldsc[i]]);
    __syncthreads();
#pragma unroll
    for (int ks = 0; ks < 2; ks++) {
      bf16x8 af[4], bfr[4];
#pragma unroll
      for (int m = 0; m < 4; m++) {
        int r = wr * 64 + m * 16 + lr;
        af[m] = *(const bf16x8*)&As[r * 64 + ((((ks << 2) + (lane >> 4)) ^ (r & 7)) << 3)];
      }
#pragma unroll
      for (int n = 0; n < 4; n++) {
        int r = wc * 64 + n * 16 + lr;
        bfr[n] = *(const bf16x8*)&Bs[r * 64 + ((((ks << 2) + (lane >> 4)) ^ (r & 7)) << 3)];
      }
#pragma unroll
      for (int m = 0; m < 4; m++)
#pragma unroll
        for (int n = 0; n < 4; n++)
          acc[m][n] = __builtin_amdgcn_mfma_f32_16x16x32_bf16(af[m], bfr[n], acc[m][n], 0, 0, 0);
    }
  }

  const int rb = tm * 128 + wr * 64 + (lane >> 4) * 4;
  const int cb = tn * 128 + wc * 64 + lr;
#pragma unroll
  for (int m = 0; m < 4; m++) {
#pragma unroll
    for (int n = 0; n < 4; n++) {
#pragma unroll
      for (int r = 0; r < 4; r++) {
        const int gi = rb + m * 16 + r;
        const int gj = cb + n * 16;
        const float v = acc[m][n][r];
        if constexpr (MODE == 0) {          // phi = exp(-max(x2+c2-2*dot,0)*sig^2)
          float ph = 0.f;
          if (gj < HID_D) {
            float d2 = fmaxf(p.x2[gi] + p.c2[gj] - 2.f * v, 0.f);
            ph = __expf(-d2 * p.sg2[gj]);
          }
          p.obf[(size_t)gi * p.ldo + gj] = f2bf(ph);
        } else if constexpr (MODE == 1) {   // h = relu(v + b1) -> fp8 e4m3
          float b = (gj < CENT_D) ? p.bias[gj] : 0.f;
          p.o8[(size_t)gi * p.ldo + gj] = f2fp8(fmaxf(v + b, 0.f));
        } else {                            // MODE 3: Ehat partial (per-z slab)
          float* of = p.of + (size_t)blockIdx.z * BDIM * IN_D;
          if (gj < IN_D) of[(size_t)gi * IN_D + gj] = v;
        }
      }
    }
  }
}

// ---------------------------------------------------------------------------
// GEMM2: MX-fp4 128x128 tile, BK=256 elems (=128B/row), cbsz=blgp=4.
// A = h fp4 (scale 1), B = w2*512 fp4.  out = exp(acc/512 + b2) -> bf16.
// ---------------------------------------------------------------------------
struct G4Args {
  const unsigned char* A;   // M x 1024 B (fp4 packed)
  const unsigned char* B;   // 2048 x 1024 B (fp4 packed)
  const float* bias;        // b2
  unsigned short* obf;      // outp bf16, ld CENTP
};

__global__ __launch_bounds__(256) void gemm_fp4(G4Args p) {
  __shared__ __align__(16) unsigned char As[128 * 128];
  __shared__ __align__(16) unsigned char Bs[128 * 128];
  const int tid  = threadIdx.x;
  const int lane = tid & 63;
  const int w    = tid >> 6;
  const int wr   = w >> 1, wc = w & 1;
  const int lr   = lane & 15;
  const int g    = lane >> 4;
  const int tm = blockIdx.x, tn = blockIdx.y;
  const int KB = CENTP / 2;   // 1024 bytes per row
  f32x4 acc[4][4] = {};

  const unsigned char* Ag = p.A + (size_t)tm * 128 * KB;
  const unsigned char* Bg = p.B + (size_t)tn * 128 * KB;

  int rowc[4], colb[4], ldsb[4];
#pragma unroll
  for (int i = 0; i < 4; i++) {
    int cc = i * 256 + tid;
    rowc[i] = cc >> 3;
    colb[i] = ((cc & 7) ^ (rowc[i] & 7)) << 4;
    ldsb[i] = cc << 4;
  }

  for (int kb0 = 0; kb0 < KB; kb0 += 128) {
    __syncthreads();
#pragma unroll
    for (int i = 0; i < 4; i++)
      g2l16(Ag + (size_t)rowc[i] * KB + kb0 + colb[i], &As[ldsb[i]]);
#pragma unroll
    for (int i = 0; i < 4; i++)
      g2l16(Bg + (size_t)rowc[i] * KB + kb0 + colb[i], &Bs[ldsb[i]]);
    __syncthreads();

#pragma unroll
    for (int ks = 0; ks < 2; ks++) {
      i32x8 bfr[4];
#pragma unroll
      for (int n = 0; n < 4; n++) {
        const int r = wc * 64 + n * 16 + lr;
        const int rb_ = r << 7, rx = r & 7;
        i32x4 v = *(const i32x4*)&Bs[rb_ + ((((ks << 2) + g) ^ rx) << 4)];
        bfr[n][0] = v[0]; bfr[n][1] = v[1]; bfr[n][2] = v[2]; bfr[n][3] = v[3];
        bfr[n][4] = 0; bfr[n][5] = 0; bfr[n][6] = 0; bfr[n][7] = 0;
      }
#pragma unroll
      for (int m = 0; m < 4; m++) {
        const int r = wr * 64 + m * 16 + lr;
        const int rb_ = r << 7, rx = r & 7;
        i32x4 v = *(const i32x4*)&As[rb_ + ((((ks << 2) + g) ^ rx) << 4)];
        i32x8 av;
        av[0] = v[0]; av[1] = v[1]; av[2] = v[2]; av[3] = v[3];
        av[4] = 0; av[5] = 0; av[6] = 0; av[7] = 0;
#pragma unroll
        for (int n = 0; n < 4; n++)
          acc[m][n] = __builtin_amdgcn_mfma_scale_f32_16x16x128_f8f6f4(
              av, bfr[n], acc[m][n], 4, 4, 0, 127, 0, 127);
      }
    }
  }

  const int rb = tm * 128 + wr * 64 + (lane >> 4) * 4;
  const int cb = tn * 128 + wc * 64 + lr;
  const float rs = 1.0f / 512.0f;   // undo w2*512
#pragma unroll
  for (int m = 0; m < 4; m++) {
#pragma unroll
    for (int n = 0; n < 4; n++) {
      const int gj = cb + n * 16;
#pragma unroll
      for (int r = 0; r < 4; r++) {
        const int gi = rb + m * 16 + r;
        float o = (gj < CENT_D) ? __expf(acc[m][n][r] * rs + p.bias[gj]) : 0.f;
        p.obf[(size_t)gi * CENTP + gj] = f2bf(o);
      }
    }
  }
}

// ---------------------------------------------------------------------------
// h fp8 (B x 2048) -> packed fp4 (B x 1024B). Fully coalesced: u64 in, u32
// out, 8 elems/thread, no divergence. 16384 blocks.
// ---------------------------------------------------------------------------
__global__ __launch_bounds__(256) void repack8to4(
    const unsigned long long* __restrict__ src, unsigned int* __restrict__ dst) {
  const size_t i = (size_t)blockIdx.x * 256 + threadIdx.x;   // u64 index
  unsigned long long v = src[i];
  unsigned u = 0;
#pragma unroll
  for (int k = 0; k < 8; k++)
    u |= f2fp4(fp8d((unsigned)(v >> (8 * k)) & 0xFFu)) << (4 * k);
  dst[i] = u;
}

// ---------------------------------------------------------------------------
// Fused cast+pad of x, centres, kern (bf16). Chunk = 4 dst bf16.
// Boundaries: x 786432 | cen 798720 | kern 929792 -> 3632 blocks.
// w1 (bf16) handled here too: | w1 1060864 -> 4144 blocks.
// ---------------------------------------------------------------------------
__global__ __launch_bounds__(256) void prep_cast(
    const float* __restrict__ x, const float* __restrict__ cen,
    const float* __restrict__ w1, const float* __restrict__ kern,
    unsigned short* __restrict__ x_bf, unsigned short* __restrict__ c_bf,
    unsigned short* __restrict__ w1p, unsigned short* __restrict__ kernp) {
  const int c = blockIdx.x * 256 + threadIdx.x;
  const float* src; unsigned short* dst; int R, C, cpq, local, vec;
  if (c < 786432)       { src = x;    dst = x_bf;  R = 16384; C = 151;  cpq = 48;  local = c;           vec = 0; }
  else if (c < 798720)  { src = cen;  dst = c_bf;  R = 200;   C = 151;  cpq = 48;  local = c - 786432;  vec = 0; }
  else if (c < 929792)  { src = w1;   dst = w1p;   R = 2000;  C = 200;  cpq = 64;  local = c - 798720;  vec = 1; }
  else                  { src = kern; dst = kernp; R = 151;   C = 2000; cpq = 512; local = c - 929792;  vec = 1; }
  const int r  = local / cpq;
  const int c4 = (local - r * cpq) << 2;
  us4 o;
  if (vec && r < R && c4 + 3 < C) {
    f4 v = *(const f4*)&src[(size_t)r * C + c4];
    o[0] = f2bf(v[0]); o[1] = f2bf(v[1]); o[2] = f2bf(v[2]); o[3] = f2bf(v[3]);
  } else {
#pragma unroll
    for (int k = 0; k < 4; k++) {
      float v = (r < R && c4 + k < C) ? src[(size_t)r * C + c4 + k] : 0.f;
      o[k] = f2bf(v);
    }
  }
  *(us4*)&dst[(size_t)local * 4] = o;
}

// w2 (2000x2000) -> fp4 e2m1 *512 (2048x1024B). 2048 blocks, 8 elems/thread.
__global__ __launch_bounds__(256) void cast_fp4(
    const float* __restrict__ src, unsigned int* __restrict__ dst) {
  const int j = blockIdx.x * 256 + threadIdx.x;   // u32 (8-elem) index
  const int r = j >> 8;                            // 256 u32 per 2048-elem row
  const int c8 = (j & 255) << 3;
  unsigned u = 0;
#pragma unroll
  for (int k = 0; k < 8; k++) {
    float v = (r < 2000 && c8 + k < 2000) ? src[(size_t)r * 2000 + c8 + k] * 512.f : 0.f;
    u |= f2fp4(v) << (4 * k);
  }
  dst[j] = u;
}

// ---------------------------------------------------------------------------
// Fused rownorm(x) + rownorm(centres) + sigmas^2.
// ---------------------------------------------------------------------------
__global__ __launch_bounds__(256) void prep_misc(
    const float* __restrict__ x, const float* __restrict__ cen,
    const float* __restrict__ sg,
    float* __restrict__ x2, float* __restrict__ c2, float* __restrict__ sg2) {
  const int b = blockIdx.x;
  if (b == 4160) {
    int j = threadIdx.x;
    sg2[j] = (j < HID_D) ? sg[j] * sg[j] : 0.f;
    return;
  }
  const float* src; float* dst; int R, base;
  if (b < 4096) { src = x;   dst = x2; R = BDIM;  base = b * 4; }
  else          { src = cen; dst = c2; R = HID_D; base = (b - 4096) * 4; }
  const int row = base + (threadIdx.x >> 6);
  const int l = threadIdx.x & 63;
  float s = 0.f;
  if (row < R)
    for (int k = l; k < IN_D; k += 64) { float v = src[(size_t)row * IN_D + k]; s += v * v; }
#pragma unroll
  for (int off = 32; off > 0; off >>= 1) s += __shfl_down(s, off);
  if (l == 0) dst[row] = s;
}

// ---------------------------------------------------------------------------
// d_out layout: [Ehat2 B*151][Rhat B*2000][Ehat2 B*151][Rhat B*2000][x B*151]
// ---------------------------------------------------------------------------
__global__ __launch_bounds__(256) void finalize(
    float* __restrict__ dout, const unsigned short* __restrict__ outp,
    const float* __restrict__ x, const float* __restrict__ part) {
  const int i = blockIdx.x;
  const size_t SL = (size_t)BDIM * IN_D;
  float* Eh = dout;
  float* Ra = dout + SL;
  float* Eb = dout + SL + (size_t)BDIM * CENT_D;
  float* Rb = Eb + SL;
  float* xo = Rb + (size_t)BDIM * CENT_D;
  const size_t ib = (size_t)i * IN_D;
  const float e0 = part[ib] + part[SL + ib] + part[2 * SL + ib] + part[3 * SL + ib];
  const float s = 1.f / e0;
  const int t = threadIdx.x;
  if (t < IN_D) {
    float v = (part[ib + t] + part[SL + ib + t] + part[2 * SL + ib + t] + part[3 * SL + ib + t]) * s;
    Eh[ib + t] = v;
    Eb[ib + t] = v;
    xo[ib + t] = x[ib + t];
  }
  if (t < 250) {
    const us8 u = *(const us8*)&outp[(size_t)i * CENTP + t * 8];
    f4 a, b;
#pragma unroll
    for (int k = 0; k < 4; k++) a[k] = bf2f(u[k]) * s;
#pragma unroll
    for (int k = 0; k < 4; k++) b[k] = bf2f(u[4 + k]) * s;
    const size_t o = (size_t)i * CENT_D + t * 8;
    *(f4*)&Ra[o] = a; *(f4*)&Ra[o + 4] = b;
    *(f4*)&Rb[o] = a; *(f4*)&Rb[o + 4] = b;
  }
}

extern "C" void kernel_launch(void* const* d_in, const int* in_sizes, int n_in,
                              void* d_out, int out_size, void* d_ws, size_t ws_size,
                              hipStream_t stream) {
  (void)in_sizes; (void)n_in; (void)out_size; (void)ws_size;
  const float* x       = (const float*)d_in[0];
  const float* centres = (const float*)d_in[1];
  const float* sigmas  = (const float*)d_in[2];
  const float* w1      = (const float*)d_in[3];
  const float* b1      = (const float*)d_in[4];
  const float* w2      = (const float*)d_in[5];
  const float* b2      = (const float*)d_in[6];
  const float* kern    = (const float*)d_in[7];
  float* dout = (float*)d_out;

  char* ws = (char*)d_ws;
  size_t off = 0;
  auto alloc = [&](size_t bytes) {
    char* p = ws + off;
    off = (off + bytes + 255) & ~(size_t)255;
    return p;
  };
  unsigned short* x_bf  = (unsigned short*)alloc((size_t)BDIM * INP * 2);
  unsigned short* c_bf  = (unsigned short*)alloc((size_t)KERNR * INP * 2);
  unsigned short* w1p   = (unsigned short*)alloc((size_t)CENTP * HIDP * 2);
  unsigned int*   w2p4  = (unsigned int*)alloc((size_t)CENTP * CENTP / 2);
  unsigned short* kernp = (unsigned short*)alloc((size_t)KERNR * CENTP * 2);
  unsigned short* phip  = (unsigned short*)alloc((size_t)BDIM * HIDP * 2);
  unsigned short* outp  = (unsigned short*)alloc((size_t)BDIM * CENTP * 2);
  unsigned int*   hp4   = (unsigned int*)alloc((size_t)BDIM * CENTP / 2);
  float* x2  = (float*)alloc((size_t)BDIM * 4);
  float* c2  = (float*)alloc((size_t)KERNR * 4);
  float* sg2 = (float*)alloc((size_t)KERNR * 4);
  float* eparts = (float*)alloc((size_t)4 * BDIM * IN_D * 4);
  // h (fp8, B x 2048 = 33.5 MB) lives in the Rhat_b output slot (131 MB);
  // consumed by repack8to4, overwritten by finalize at the end.
  unsigned char* hp8 = (unsigned char*)(dout + (size_t)BDIM * (2 * IN_D + CENT_D));

  prep_cast<<<4144, 256, 0, stream>>>(x, centres, w1, kern, x_bf, c_bf, w1p, kernp);
  cast_fp4<<<2048, 256, 0, stream>>>(w2, w2p4);
  prep_misc<<<4161, 256, 0, stream>>>(x, centres, sigmas, x2, c2, sg2);

  // GEMM0: phi -> bf16  (M=16384, N=256, K=192)   [round-5 exact]
  GArgs g0{}; g0.A = x_bf; g0.B = c_bf; g0.K = INP; g0.kspan = INP;
  g0.x2 = x2; g0.c2 = c2; g0.sg2 = sg2; g0.obf = phip; g0.ldo = HIDP;
  gemm_bt<0><<<dim3(BDIM / 128, HIDP / 128, 1), 256, 0, stream>>>(g0);

  // GEMM1: h = relu(phi @ w1^T + b1) -> fp8  (bf16, K=256)   [round-5 exact]
  GArgs g1{}; g1.A = phip; g1.B = w1p; g1.K = HIDP; g1.kspan = HIDP;
  g1.bias = b1; g1.o8 = hp8; g1.ldo = CENTP;
  gemm_bt<1><<<dim3(BDIM / 128, CENTP / 128, 1), 256, 0, stream>>>(g1);

  // repack h fp8 -> fp4 packed (coalesced, ~8 us)
  repack8to4<<<(int)((size_t)BDIM * CENTP / 8 / 256), 256, 0, stream>>>(
      (const unsigned long long*)hp8, hp4);

  // GEMM2: out = exp((h @ (512*w2)^T)/512 + b2)  (MX-fp4, K=2048)
  G4Args g2{}; g2.A = (const unsigned char*)hp4; g2.B = (const unsigned char*)w2p4;
  g2.bias = b2; g2.obf = outp;
  gemm_fp4<<<dim3(BDIM / 128, CENTP / 128), 256, 0, stream>>>(g2);

  // GEMM3: Ehat partials, split-K x4 (bf16, 1024 blocks)   [round-5 exact]
  GArgs g3{}; g3.A = outp; g3.B = kernp; g3.K = CENTP; g3.kspan = CENTP / 4;
  g3.of = eparts;
  gemm_bt<3><<<dim3(BDIM / 128, KERNR / 128, 4), 256, 0, stream>>>(g3);

  finalize<<<BDIM, 256, 0, stream>>>(dout, outp, x, eparts);
}

// Round 8
// 244.347 us; speedup vs baseline: 1.5383x; 1.5383x over previous
//
#include <hip/hip_runtime.h>

#define BDIM 16384
#define IN_D 151
#define HID_D 200
#define CENT_D 2000

#define INP 192     // K of GEMM0
#define HIDP 256    // N of GEMM0, K of GEMM1
#define CENTP 2048  // N of GEMM1/2, K of GEMM2/3
#define KERN_R 192  // kern rows padded (N of GEMM3)

using bf16x8 = __attribute__((ext_vector_type(8))) short;
using f32x4  = __attribute__((ext_vector_type(4))) float;
using f4     = __attribute__((ext_vector_type(4))) float;
using us4    = __attribute__((ext_vector_type(4))) unsigned short;
using us8    = __attribute__((ext_vector_type(8))) unsigned short;
using i32x4  = __attribute__((ext_vector_type(4))) int;
using i32x8  = __attribute__((ext_vector_type(8))) int;

__device__ __forceinline__ unsigned short f2bf(float f) {
  unsigned u = __builtin_bit_cast(unsigned, f);
  u += 0x7FFFu + ((u >> 16) & 1u);
  return (unsigned short)(u >> 16);
}
__device__ __forceinline__ float bf2f(unsigned short h) {
  unsigned u = ((unsigned)h) << 16;
  return __builtin_bit_cast(float, u);
}
__device__ __forceinline__ unsigned char f2fp8(float f) {
  return (unsigned char)(__builtin_amdgcn_cvt_pk_fp8_f32(f, f, 0, false) & 0xFF);
}

typedef __attribute__((address_space(1))) const unsigned int guint;
typedef __attribute__((address_space(3))) unsigned int luint;
__device__ __forceinline__ void g2l16(const void* g, void* l) {
  __builtin_amdgcn_global_load_lds((guint*)g, (luint*)l, 16, 0, 0);
}

// ---------------------------------------------------------------------------
// GEMM0: bf16 128x128 tile, BK=64, 4 waves. phi -> fp8 e4m3.
// ---------------------------------------------------------------------------
struct G0Args {
  const unsigned short* A;   // x_bf: 16384 x 192 bf16
  const unsigned short* B;   // c_bf: 256 x 192 bf16
  const float* x2; const float* c2; const float* sg2;
  unsigned char* o8;         // phip8: 16384 x 256 fp8
};

__global__ __launch_bounds__(256) void gemm_phi(G0Args p) {
  __shared__ __align__(16) short As[128 * 64];
  __shared__ __align__(16) short Bs[128 * 64];
  const int tid  = threadIdx.x;
  const int lane = tid & 63;
  const int w    = tid >> 6;
  const int wr   = w >> 1, wc = w & 1;
  const int lr   = lane & 15;
  const int tm = blockIdx.x, tn = blockIdx.y;
  f32x4 acc[4][4] = {};

  const unsigned short* Ag = p.A + (size_t)tm * 128 * INP;
  const unsigned short* Bg = p.B + (size_t)tn * 128 * INP;

  int rowc[4], colc[4], ldsc[4];
#pragma unroll
  for (int i = 0; i < 4; i++) {
    int cc = i * 256 + tid;
    rowc[i] = cc >> 3;
    colc[i] = ((cc & 7) ^ (rowc[i] & 7)) * 8;
    ldsc[i] = cc * 8;
  }

  for (int k0 = 0; k0 < INP; k0 += 64) {
    __syncthreads();
#pragma unroll
    for (int i = 0; i < 4; i++)
      g2l16(Ag + (size_t)rowc[i] * INP + k0 + colc[i], &As[ldsc[i]]);
#pragma unroll
    for (int i = 0; i < 4; i++)
      g2l16(Bg + (size_t)rowc[i] * INP + k0 + colc[i], &Bs[ldsc[i]]);
    __syncthreads();
#pragma unroll
    for (int ks = 0; ks < 2; ks++) {
      bf16x8 af[4], bfr[4];
#pragma unroll
      for (int m = 0; m < 4; m++) {
        int r = wr * 64 + m * 16 + lr;
        af[m] = *(const bf16x8*)&As[r * 64 + ((((ks << 2) + (lane >> 4)) ^ (r & 7)) << 3)];
      }
#pragma unroll
      for (int n = 0; n < 4; n++) {
        int r = wc * 64 + n * 16 + lr;
        bfr[n] = *(const bf16x8*)&Bs[r * 64 + ((((ks << 2) + (lane >> 4)) ^ (r & 7)) << 3)];
      }
#pragma unroll
      for (int m = 0; m < 4; m++)
#pragma unroll
        for (int n = 0; n < 4; n++)
          acc[m][n] = __builtin_amdgcn_mfma_f32_16x16x32_bf16(af[m], bfr[n], acc[m][n], 0, 0, 0);
    }
  }

  const int rb = tm * 128 + wr * 64 + (lane >> 4) * 4;
  const int cb = tn * 128 + wc * 64 + lr;
#pragma unroll
  for (int m = 0; m < 4; m++) {
#pragma unroll
    for (int n = 0; n < 4; n++) {
      const int gj = cb + n * 16;
#pragma unroll
      for (int r = 0; r < 4; r++) {
        const int gi = rb + m * 16 + r;
        float ph = 0.f;
        if (gj < HID_D) {
          float d2 = fmaxf(p.x2[gi] + p.c2[gj] - 2.f * acc[m][n][r], 0.f);
          ph = __expf(-d2 * p.sg2[gj]);
        }
        p.o8[(size_t)gi * HIDP + gj] = f2fp8(ph);
      }
    }
  }
}

// ---------------------------------------------------------------------------
// MX-fp8 128x128 tile, BK=128B, identity scales (round-5 proven body).
// MODE 1: h = relu(acc/8 + b1) -> fp8      (GEMM1: A=phi8, B=w1*8)
// MODE 2: out = exp(acc/256 + b2) -> bf16  (GEMM2: A=h8,   B=w2*256)
// ---------------------------------------------------------------------------
struct G8Args {
  const unsigned char* A;
  const unsigned char* B;
  int K;
  const float* bias;
  unsigned short* obf;       // MODE 2
  unsigned char* o8;         // MODE 1
};

template<int MODE>
__global__ __launch_bounds__(256) void gemm_fp8(G8Args p) {
  __shared__ __align__(16) unsigned char As[128 * 128];
  __shared__ __align__(16) unsigned char Bs[128 * 128];
  const int tid  = threadIdx.x;
  const int lane = tid & 63;
  const int w    = tid >> 6;
  const int wr   = w >> 1, wc = w & 1;
  const int lr   = lane & 15;
  const int g    = lane >> 4;
  const int tm = blockIdx.x, tn = blockIdx.y;
  const int K = p.K;
  f32x4 acc[4][4] = {};

  const unsigned char* Ag = p.A + (size_t)tm * 128 * K;
  const unsigned char* Bg = p.B + (size_t)tn * 128 * K;

  int rowc[4], colb[4], ldsb[4];
#pragma unroll
  for (int i = 0; i < 4; i++) {
    int cc = i * 256 + tid;
    rowc[i] = cc >> 3;
    colb[i] = ((cc & 7) ^ (rowc[i] & 7)) << 4;
    ldsb[i] = cc << 4;
  }

  for (int k0 = 0; k0 < K; k0 += 128) {
    __syncthreads();
#pragma unroll
    for (int i = 0; i < 4; i++)
      g2l16(Ag + (size_t)rowc[i] * K + k0 + colb[i], &As[ldsb[i]]);
#pragma unroll
    for (int i = 0; i < 4; i++)
      g2l16(Bg + (size_t)rowc[i] * K + k0 + colb[i], &Bs[ldsb[i]]);
    __syncthreads();

    i32x8 bfr[4];
#pragma unroll
    for (int n = 0; n < 4; n++) {
      const int r = wc * 64 + n * 16 + lr;
      const int rb_ = r << 7, rx = r & 7;
      i32x4 lo = *(const i32x4*)&Bs[rb_ + (((2 * g) ^ rx) << 4)];
      i32x4 hi = *(const i32x4*)&Bs[rb_ + (((2 * g + 1) ^ rx) << 4)];
      bfr[n][0] = lo[0]; bfr[n][1] = lo[1]; bfr[n][2] = lo[2]; bfr[n][3] = lo[3];
      bfr[n][4] = hi[0]; bfr[n][5] = hi[1]; bfr[n][6] = hi[2]; bfr[n][7] = hi[3];
    }
#pragma unroll
    for (int m = 0; m < 4; m++) {
      const int r = wr * 64 + m * 16 + lr;
      const int rb_ = r << 7, rx = r & 7;
      i32x4 lo = *(const i32x4*)&As[rb_ + (((2 * g) ^ rx) << 4)];
      i32x4 hi = *(const i32x4*)&As[rb_ + (((2 * g + 1) ^ rx) << 4)];
      i32x8 av;
      av[0] = lo[0]; av[1] = lo[1]; av[2] = lo[2]; av[3] = lo[3];
      av[4] = hi[0]; av[5] = hi[1]; av[6] = hi[2]; av[7] = hi[3];
#pragma unroll
      for (int n = 0; n < 4; n++)
        acc[m][n] = __builtin_amdgcn_mfma_scale_f32_16x16x128_f8f6f4(
            av, bfr[n], acc[m][n], 0, 0, 0, 127, 0, 127);
    }
  }

  const int rb = tm * 128 + wr * 64 + (lane >> 4) * 4;
  const int cb = tn * 128 + wc * 64 + lr;
  const float rs = (MODE == 1) ? 0.125f : (1.0f / 256.0f);
#pragma unroll
  for (int m = 0; m < 4; m++) {
#pragma unroll
    for (int n = 0; n < 4; n++) {
      const int gj = cb + n * 16;
      const float b = (gj < CENT_D) ? p.bias[gj] : 0.f;
#pragma unroll
      for (int r = 0; r < 4; r++) {
        const int gi = rb + m * 16 + r;
        if constexpr (MODE == 1) {
          p.o8[(size_t)gi * CENTP + gj] = f2fp8(fmaxf(acc[m][n][r] * rs + b, 0.f));
        } else {
          float o = (gj < CENT_D) ? __expf(acc[m][n][r] * rs + b) : 0.f;
          p.obf[(size_t)gi * CENTP + gj] = f2bf(o);
        }
      }
    }
  }
}

// ---------------------------------------------------------------------------
// GEMM3: Ehat partials. BN=192 held per block (outp read ONCE), split-K x4
// via blockIdx.y. bf16, BK=64, 4 waves (2M x 2N), acc[4][6]/wave.
// ---------------------------------------------------------------------------
struct G3Args {
  const unsigned short* A;   // outp: 16384 x 2048 bf16
  const unsigned short* B;   // kernp: 192 x 2048 bf16
  float* of;                 // eparts: [4][16384][151] f32
  int kspan;                 // 512
};

__global__ __launch_bounds__(256, 1) void gemm3w(G3Args p) {
  __shared__ __align__(16) short As[128 * 64];
  __shared__ __align__(16) short Bs[KERN_R * 64];
  const int tid  = threadIdx.x;
  const int lane = tid & 63;
  const int w    = tid >> 6;
  const int wr   = w >> 1, wc = w & 1;
  const int lr   = lane & 15;
  const int tm = blockIdx.x;
  const int kbeg = blockIdx.y * p.kspan;
  f32x4 acc[4][6] = {};

  const unsigned short* Ag = p.A + (size_t)tm * 128 * CENTP;
  const unsigned short* Bg = p.B;

  int rowa[4], cola[4], lda_[4];
#pragma unroll
  for (int i = 0; i < 4; i++) {
    int cc = i * 256 + tid;
    rowa[i] = cc >> 3;
    cola[i] = ((cc & 7) ^ (rowa[i] & 7)) * 8;
    lda_[i] = cc * 8;
  }
  int rowb[6], colbb[6], ldb_[6];
#pragma unroll
  for (int i = 0; i < 6; i++) {
    int cc = i * 256 + tid;                 // 1536 chunks = 192 rows x 8
    rowb[i] = cc >> 3;
    colbb[i] = ((cc & 7) ^ (rowb[i] & 7)) * 8;
    ldb_[i] = cc * 8;
  }

  for (int k0 = kbeg; k0 < kbeg + p.kspan; k0 += 64) {
    __syncthreads();
#pragma unroll
    for (int i = 0; i < 4; i++)
      g2l16(Ag + (size_t)rowa[i] * CENTP + k0 + cola[i], &As[lda_[i]]);
#pragma unroll
    for (int i = 0; i < 6; i++)
      g2l16(Bg + (size_t)rowb[i] * CENTP + k0 + colbb[i], &Bs[ldb_[i]]);
    __syncthreads();
#pragma unroll
    for (int ks = 0; ks < 2; ks++) {
      bf16x8 af[4], bfr[6];
#pragma unroll
      for (int m = 0; m < 4; m++) {
        int r = wr * 64 + m * 16 + lr;
        af[m] = *(const bf16x8*)&As[r * 64 + ((((ks << 2) + (lane >> 4)) ^ (r & 7)) << 3)];
      }
#pragma unroll
      for (int n = 0; n < 6; n++) {
        int r = wc * 96 + n * 16 + lr;
        bfr[n] = *(const bf16x8*)&Bs[r * 64 + ((((ks << 2) + (lane >> 4)) ^ (r & 7)) << 3)];
      }
#pragma unroll
      for (int m = 0; m < 4; m++)
#pragma unroll
        for (int n = 0; n < 6; n++)
          acc[m][n] = __builtin_amdgcn_mfma_f32_16x16x32_bf16(af[m], bfr[n], acc[m][n], 0, 0, 0);
    }
  }

  float* of = p.of + (size_t)blockIdx.y * BDIM * IN_D;
  const int rb = tm * 128 + wr * 64 + (lane >> 4) * 4;
  const int cb = wc * 96 + lr;
#pragma unroll
  for (int m = 0; m < 4; m++) {
#pragma unroll
    for (int n = 0; n < 6; n++) {
      const int gj = cb + n * 16;
#pragma unroll
      for (int r = 0; r < 4; r++) {
        const int gi = rb + m * 16 + r;
        if (gj < IN_D) of[(size_t)gi * IN_D + gj] = acc[m][n][r];
      }
    }
  }
}

// ---------------------------------------------------------------------------
// Fused cast+pad of x, centres, kern (bf16). Chunk = 4 dst bf16.
// Boundaries: x 786432 | cen 798720 | kern 897024 -> 3504 blocks.
// ---------------------------------------------------------------------------
__global__ __launch_bounds__(256) void prep_cast(
    const float* __restrict__ x, const float* __restrict__ cen,
    const float* __restrict__ kern,
    unsigned short* __restrict__ x_bf, unsigned short* __restrict__ c_bf,
    unsigned short* __restrict__ kernp) {
  const int c = blockIdx.x * 256 + threadIdx.x;
  const float* src; unsigned short* dst; int R, C, cpq, local, vec;
  if (c < 786432)       { src = x;    dst = x_bf;  R = 16384; C = 151;  cpq = 48;  local = c;           vec = 0; }
  else if (c < 798720)  { src = cen;  dst = c_bf;  R = 200;   C = 151;  cpq = 48;  local = c - 786432;  vec = 0; }
  else                  { src = kern; dst = kernp; R = 151;   C = 2000; cpq = 512; local = c - 798720;  vec = 1; }
  const int r  = local / cpq;
  const int c4 = (local - r * cpq) << 2;
  us4 o;
  if (vec && r < R && c4 + 3 < C) {
    f4 v = *(const f4*)&src[(size_t)r * C + c4];
    o[0] = f2bf(v[0]); o[1] = f2bf(v[1]); o[2] = f2bf(v[2]); o[3] = f2bf(v[3]);
  } else {
#pragma unroll
    for (int k = 0; k < 4; k++) {
      float v = (r < R && c4 + k < C) ? src[(size_t)r * C + c4 + k] : 0.f;
      o[k] = f2bf(v);
    }
  }
  *(us4*)&dst[(size_t)local * 4] = o;
}

// ---------------------------------------------------------------------------
// w1 (2000x200) -> fp8*8 (2048x256); w2 (2000x2000) -> fp8*256 (2048x2048).
// uint space: w1 131072 | w2 +1048576 = 1179648 -> 4608 blocks.
// ---------------------------------------------------------------------------
__global__ __launch_bounds__(256) void prep_lowp(
    const float* __restrict__ w1, const float* __restrict__ w2,
    unsigned char* __restrict__ w1p8, unsigned char* __restrict__ w2p8) {
  const int i = blockIdx.x * 256 + threadIdx.x;
  const float* src; unsigned char* dst; int r, c4, R, C; float sc;
  int j;
  if (i < 131072) { src = w1; dst = w1p8; j = i;          r = j >> 6; c4 = (j & 63) << 2;  R = 2000; C = 200;  sc = 8.f; }
  else            { src = w2; dst = w2p8; j = i - 131072; r = j >> 9; c4 = (j & 511) << 2; R = 2000; C = 2000; sc = 256.f; }
  float v[4];
#pragma unroll
  for (int k = 0; k < 4; k++)
    v[k] = (r < R && c4 + k < C) ? src[(size_t)r * C + c4 + k] * sc : 0.f;
  int p0 = __builtin_amdgcn_cvt_pk_fp8_f32(v[0], v[1], 0, false);
  int p1 = __builtin_amdgcn_cvt_pk_fp8_f32(v[2], v[3], 0, false);
  *(unsigned int*)&dst[(size_t)j * 4] =
      ((unsigned)p0 & 0xFFFFu) | (((unsigned)p1 & 0xFFFFu) << 16);
}

// ---------------------------------------------------------------------------
// Fused rownorm(x) + rownorm(centres) + sigmas^2.
// ---------------------------------------------------------------------------
__global__ __launch_bounds__(256) void prep_misc(
    const float* __restrict__ x, const float* __restrict__ cen,
    const float* __restrict__ sg,
    float* __restrict__ x2, float* __restrict__ c2, float* __restrict__ sg2) {
  const int b = blockIdx.x;
  if (b == 4160) {
    int j = threadIdx.x;
    sg2[j] = (j < HID_D) ? sg[j] * sg[j] : 0.f;
    return;
  }
  const float* src; float* dst; int R, base;
  if (b < 4096) { src = x;   dst = x2; R = BDIM;  base = b * 4; }
  else          { src = cen; dst = c2; R = HID_D; base = (b - 4096) * 4; }
  const int row = base + (threadIdx.x >> 6);
  const int l = threadIdx.x & 63;
  float s = 0.f;
  if (row < R)
    for (int k = l; k < IN_D; k += 64) { float v = src[(size_t)row * IN_D + k]; s += v * v; }
#pragma unroll
  for (int off = 32; off > 0; off >>= 1) s += __shfl_down(s, off);
  if (l == 0) dst[row] = s;
}

// ---------------------------------------------------------------------------
// d_out layout: [Ehat2 B*151][Rhat B*2000][Ehat2 B*151][Rhat B*2000][x B*151]
// ---------------------------------------------------------------------------
__global__ __launch_bounds__(256) void finalize(
    float* __restrict__ dout, const unsigned short* __restrict__ outp,
    const float* __restrict__ x, const float* __restrict__ part) {
  const int i = blockIdx.x;
  const size_t SL = (size_t)BDIM * IN_D;
  float* Eh = dout;
  float* Ra = dout + SL;
  float* Eb = dout + SL + (size_t)BDIM * CENT_D;
  float* Rb = Eb + SL;
  float* xo = Rb + (size_t)BDIM * CENT_D;
  const size_t ib = (size_t)i * IN_D;
  const float e0 = part[ib] + part[SL + ib] + part[2 * SL + ib] + part[3 * SL + ib];
  const float s = 1.f / e0;
  const int t = threadIdx.x;
  if (t < IN_D) {
    float v = (part[ib + t] + part[SL + ib + t] + part[2 * SL + ib + t] + part[3 * SL + ib + t]) * s;
    Eh[ib + t] = v;
    Eb[ib + t] = v;
    xo[ib + t] = x[ib + t];
  }
  if (t < 250) {
    const us8 u = *(const us8*)&outp[(size_t)i * CENTP + t * 8];
    f4 a, b;
#pragma unroll
    for (int k = 0; k < 4; k++) a[k] = bf2f(u[k]) * s;
#pragma unroll
    for (int k = 0; k < 4; k++) b[k] = bf2f(u[4 + k]) * s;
    const size_t o = (size_t)i * CENT_D + t * 8;
    *(f4*)&Ra[o] = a; *(f4*)&Ra[o + 4] = b;
    *(f4*)&Rb[o] = a; *(f4*)&Rb[o + 4] = b;
  }
}

extern "C" void kernel_launch(void* const* d_in, const int* in_sizes, int n_in,
                              void* d_out, int out_size, void* d_ws, size_t ws_size,
                              hipStream_t stream) {
  (void)in_sizes; (void)n_in; (void)out_size; (void)ws_size;
  const float* x       = (const float*)d_in[0];
  const float* centres = (const float*)d_in[1];
  const float* sigmas  = (const float*)d_in[2];
  const float* w1      = (const float*)d_in[3];
  const float* b1      = (const float*)d_in[4];
  const float* w2      = (const float*)d_in[5];
  const float* b2      = (const float*)d_in[6];
  const float* kern    = (const float*)d_in[7];
  float* dout = (float*)d_out;

  char* ws = (char*)d_ws;
  size_t off = 0;
  auto alloc = [&](size_t bytes) {
    char* p = ws + off;
    off = (off + bytes + 255) & ~(size_t)255;
    return p;
  };
  unsigned short* x_bf  = (unsigned short*)alloc((size_t)BDIM * INP * 2);
  unsigned short* c_bf  = (unsigned short*)alloc((size_t)256 * INP * 2);
  unsigned char*  w1p8  = (unsigned char*)alloc((size_t)CENTP * HIDP);
  unsigned char*  w2p8  = (unsigned char*)alloc((size_t)CENTP * CENTP);
  unsigned short* kernp = (unsigned short*)alloc((size_t)KERN_R * CENTP * 2);
  unsigned char*  phip8 = (unsigned char*)alloc((size_t)BDIM * HIDP);
  unsigned short* outp  = (unsigned short*)alloc((size_t)BDIM * CENTP * 2);
  float* x2  = (float*)alloc((size_t)BDIM * 4);
  float* c2  = (float*)alloc((size_t)256 * 4);
  float* sg2 = (float*)alloc((size_t)256 * 4);
  float* eparts = (float*)alloc((size_t)4 * BDIM * IN_D * 4);
  // h (fp8, B x 2048 = 33.5 MB) lives in the Rhat_b output slot (131 MB);
  // consumed by GEMM2, overwritten by finalize at the end.
  unsigned char* hp8 = (unsigned char*)(dout + (size_t)BDIM * (2 * IN_D + CENT_D));

  prep_cast<<<3504, 256, 0, stream>>>(x, centres, kern, x_bf, c_bf, kernp);
  prep_lowp<<<4608, 256, 0, stream>>>(w1, w2, w1p8, w2p8);
  prep_misc<<<4161, 256, 0, stream>>>(x, centres, sigmas, x2, c2, sg2);

  // GEMM0: phi -> fp8  (M=16384, N=256, K=192)
  G0Args g0{}; g0.A = x_bf; g0.B = c_bf;
  g0.x2 = x2; g0.c2 = c2; g0.sg2 = sg2; g0.o8 = phip8;
  gemm_phi<<<dim3(BDIM / 128, HIDP / 128), 256, 0, stream>>>(g0);

  // GEMM1: h = relu((phi @ (8*w1)^T)/8 + b1) -> fp8  (MX-fp8, K=256)
  G8Args g1{}; g1.A = phip8; g1.B = w1p8; g1.K = HIDP;
  g1.bias = b1; g1.o8 = hp8;
  gemm_fp8<1><<<dim3(BDIM / 128, CENTP / 128), 256, 0, stream>>>(g1);

  // GEMM2: out = exp((h @ (256*w2)^T)/256 + b2) -> bf16  (MX-fp8, K=2048)
  G8Args g2{}; g2.A = hp8; g2.B = w2p8; g2.K = CENTP;
  g2.bias = b2; g2.obf = outp;
  gemm_fp8<2><<<dim3(BDIM / 128, CENTP / 128), 256, 0, stream>>>(g2);

  // GEMM3: Ehat partials (bf16, outp read once, split-K x4 -> 512 blocks)
  G3Args g3{}; g3.A = outp; g3.B = kernp; g3.of = eparts; g3.kspan = CENTP / 4;
  gemm3w<<<dim3(BDIM / 128, 4), 256, 0, stream>>>(g3);

  finalize<<<BDIM, 256, 0, stream>>>(dout, outp, x, eparts);
}

// Round 9
// 232.571 us; speedup vs baseline: 1.6162x; 1.0506x over previous
//
#include <hip/hip_runtime.h>

#define BDIM 16384
#define IN_D 151
#define HID_D 200
#define CENT_D 2000

#define INP 192     // K of GEMM0
#define HIDP 256    // N of GEMM0, K of GEMM1
#define CENTP 2048  // N of GEMM1/2, K of GEMM2/3
#define KERN_R 192  // kern rows padded (N of GEMM3)

using bf16x8 = __attribute__((ext_vector_type(8))) short;
using f32x4  = __attribute__((ext_vector_type(4))) float;
using f4     = __attribute__((ext_vector_type(4))) float;
using us4    = __attribute__((ext_vector_type(4))) unsigned short;
using us8    = __attribute__((ext_vector_type(8))) unsigned short;
using i32x4  = __attribute__((ext_vector_type(4))) int;
using i32x8  = __attribute__((ext_vector_type(8))) int;

__device__ __forceinline__ unsigned short f2bf(float f) {
  unsigned u = __builtin_bit_cast(unsigned, f);
  u += 0x7FFFu + ((u >> 16) & 1u);
  return (unsigned short)(u >> 16);
}
__device__ __forceinline__ float bf2f(unsigned short h) {
  unsigned u = ((unsigned)h) << 16;
  return __builtin_bit_cast(float, u);
}
__device__ __forceinline__ unsigned char f2fp8(float f) {
  return (unsigned char)(__builtin_amdgcn_cvt_pk_fp8_f32(f, f, 0, false) & 0xFF);
}

typedef __attribute__((address_space(1))) const unsigned int guint;
typedef __attribute__((address_space(3))) unsigned int luint;
__device__ __forceinline__ void g2l16(const void* g, void* l) {
  __builtin_amdgcn_global_load_lds((guint*)g, (luint*)l, 16, 0, 0);
}

// ---------------------------------------------------------------------------
// GEMM0: bf16 64x128 tile, BK=64, 4 waves (2Mx2N), 512 blocks (2/CU).
// phi -> fp8 e4m3.
// ---------------------------------------------------------------------------
struct G0Args {
  const unsigned short* A;   // x_bf: 16384 x 192 bf16
  const unsigned short* B;   // c_bf: 256 x 192 bf16
  const float* x2; const float* c2; const float* sg2;
  unsigned char* o8;         // phip8: 16384 x 256 fp8
};

__global__ __launch_bounds__(256) void gemm_phi(G0Args p) {
  __shared__ __align__(16) short As[64 * 64];
  __shared__ __align__(16) short Bs[128 * 64];
  const int tid  = threadIdx.x;
  const int lane = tid & 63;
  const int w    = tid >> 6;
  const int wr   = w >> 1, wc = w & 1;
  const int lr   = lane & 15;
  const int tm = blockIdx.x, tn = blockIdx.y;
  f32x4 acc[2][4] = {};

  const unsigned short* Ag = p.A + (size_t)tm * 64 * INP;
  const unsigned short* Bg = p.B + (size_t)tn * 128 * INP;

  int rowa[2], cola[2], lda_[2];
#pragma unroll
  for (int i = 0; i < 2; i++) {
    int cc = i * 256 + tid;          // 512 chunks = 64 rows x 8
    rowa[i] = cc >> 3;
    cola[i] = ((cc & 7) ^ (rowa[i] & 7)) * 8;
    lda_[i] = cc * 8;
  }
  int rowb[4], colb[4], ldb_[4];
#pragma unroll
  for (int i = 0; i < 4; i++) {
    int cc = i * 256 + tid;
    rowb[i] = cc >> 3;
    colb[i] = ((cc & 7) ^ (rowb[i] & 7)) * 8;
    ldb_[i] = cc * 8;
  }

  for (int k0 = 0; k0 < INP; k0 += 64) {
    __syncthreads();
#pragma unroll
    for (int i = 0; i < 2; i++)
      g2l16(Ag + (size_t)rowa[i] * INP + k0 + cola[i], &As[lda_[i]]);
#pragma unroll
    for (int i = 0; i < 4; i++)
      g2l16(Bg + (size_t)rowb[i] * INP + k0 + colb[i], &Bs[ldb_[i]]);
    __syncthreads();
#pragma unroll
    for (int ks = 0; ks < 2; ks++) {
      bf16x8 af[2], bfr[4];
#pragma unroll
      for (int m = 0; m < 2; m++) {
        int r = wr * 32 + m * 16 + lr;
        af[m] = *(const bf16x8*)&As[r * 64 + ((((ks << 2) + (lane >> 4)) ^ (r & 7)) << 3)];
      }
#pragma unroll
      for (int n = 0; n < 4; n++) {
        int r = wc * 64 + n * 16 + lr;
        bfr[n] = *(const bf16x8*)&Bs[r * 64 + ((((ks << 2) + (lane >> 4)) ^ (r & 7)) << 3)];
      }
#pragma unroll
      for (int m = 0; m < 2; m++)
#pragma unroll
        for (int n = 0; n < 4; n++)
          acc[m][n] = __builtin_amdgcn_mfma_f32_16x16x32_bf16(af[m], bfr[n], acc[m][n], 0, 0, 0);
    }
  }

  const int rb = tm * 64 + wr * 32 + (lane >> 4) * 4;
  const int cb = tn * 128 + wc * 64 + lr;
#pragma unroll
  for (int m = 0; m < 2; m++) {
#pragma unroll
    for (int n = 0; n < 4; n++) {
      const int gj = cb + n * 16;
#pragma unroll
      for (int r = 0; r < 4; r++) {
        const int gi = rb + m * 16 + r;
        float ph = 0.f;
        if (gj < HID_D) {
          float d2 = fmaxf(p.x2[gi] + p.c2[gj] - 2.f * acc[m][n][r], 0.f);
          ph = __expf(-d2 * p.sg2[gj]);
        }
        p.o8[(size_t)gi * HIDP + gj] = f2fp8(ph);
      }
    }
  }
}

// ---------------------------------------------------------------------------
// MX-fp8 128x128 tile, BK=128B, identity scales (round-5 proven body).
// MODE 1: h = relu(acc/8 + b1) -> fp8      (GEMM1: A=phi8, B=w1*8)
// MODE 2: out = exp(acc/256 + b2) -> bf16  (GEMM2: A=h8,   B=w2*256)
// ---------------------------------------------------------------------------
struct G8Args {
  const unsigned char* A;
  const unsigned char* B;
  int K;
  const float* bias;
  unsigned short* obf;       // MODE 2
  unsigned char* o8;         // MODE 1
};

template<int MODE>
__global__ __launch_bounds__(256) void gemm_fp8(G8Args p) {
  __shared__ __align__(16) unsigned char As[128 * 128];
  __shared__ __align__(16) unsigned char Bs[128 * 128];
  const int tid  = threadIdx.x;
  const int lane = tid & 63;
  const int w    = tid >> 6;
  const int wr   = w >> 1, wc = w & 1;
  const int lr   = lane & 15;
  const int g    = lane >> 4;
  const int tm = blockIdx.x, tn = blockIdx.y;
  const int K = p.K;
  f32x4 acc[4][4] = {};

  const unsigned char* Ag = p.A + (size_t)tm * 128 * K;
  const unsigned char* Bg = p.B + (size_t)tn * 128 * K;

  int rowc[4], colb[4], ldsb[4];
#pragma unroll
  for (int i = 0; i < 4; i++) {
    int cc = i * 256 + tid;
    rowc[i] = cc >> 3;
    colb[i] = ((cc & 7) ^ (rowc[i] & 7)) << 4;
    ldsb[i] = cc << 4;
  }

  for (int k0 = 0; k0 < K; k0 += 128) {
    __syncthreads();
#pragma unroll
    for (int i = 0; i < 4; i++)
      g2l16(Ag + (size_t)rowc[i] * K + k0 + colb[i], &As[ldsb[i]]);
#pragma unroll
    for (int i = 0; i < 4; i++)
      g2l16(Bg + (size_t)rowc[i] * K + k0 + colb[i], &Bs[ldsb[i]]);
    __syncthreads();

    i32x8 bfr[4];
#pragma unroll
    for (int n = 0; n < 4; n++) {
      const int r = wc * 64 + n * 16 + lr;
      const int rb_ = r << 7, rx = r & 7;
      i32x4 lo = *(const i32x4*)&Bs[rb_ + (((2 * g) ^ rx) << 4)];
      i32x4 hi = *(const i32x4*)&Bs[rb_ + (((2 * g + 1) ^ rx) << 4)];
      bfr[n][0] = lo[0]; bfr[n][1] = lo[1]; bfr[n][2] = lo[2]; bfr[n][3] = lo[3];
      bfr[n][4] = hi[0]; bfr[n][5] = hi[1]; bfr[n][6] = hi[2]; bfr[n][7] = hi[3];
    }
#pragma unroll
    for (int m = 0; m < 4; m++) {
      const int r = wr * 64 + m * 16 + lr;
      const int rb_ = r << 7, rx = r & 7;
      i32x4 lo = *(const i32x4*)&As[rb_ + (((2 * g) ^ rx) << 4)];
      i32x4 hi = *(const i32x4*)&As[rb_ + (((2 * g + 1) ^ rx) << 4)];
      i32x8 av;
      av[0] = lo[0]; av[1] = lo[1]; av[2] = lo[2]; av[3] = lo[3];
      av[4] = hi[0]; av[5] = hi[1]; av[6] = hi[2]; av[7] = hi[3];
#pragma unroll
      for (int n = 0; n < 4; n++)
        acc[m][n] = __builtin_amdgcn_mfma_scale_f32_16x16x128_f8f6f4(
            av, bfr[n], acc[m][n], 0, 0, 0, 127, 0, 127);
    }
  }

  const int rb = tm * 128 + wr * 64 + (lane >> 4) * 4;
  const int cb = tn * 128 + wc * 64 + lr;
  const float rs = (MODE == 1) ? 0.125f : (1.0f / 256.0f);
#pragma unroll
  for (int m = 0; m < 4; m++) {
#pragma unroll
    for (int n = 0; n < 4; n++) {
      const int gj = cb + n * 16;
      const float b = (gj < CENT_D) ? p.bias[gj] : 0.f;
#pragma unroll
      for (int r = 0; r < 4; r++) {
        const int gi = rb + m * 16 + r;
        if constexpr (MODE == 1) {
          p.o8[(size_t)gi * CENTP + gj] = f2fp8(fmaxf(acc[m][n][r] * rs + b, 0.f));
        } else {
          float o = (gj < CENT_D) ? __expf(acc[m][n][r] * rs + b) : 0.f;
          p.obf[(size_t)gi * CENTP + gj] = f2bf(o);
        }
      }
    }
  }
}

// ---------------------------------------------------------------------------
// GEMM3: Ehat partials. BN=192 held per block (outp read ONCE), split-K x2
// via blockIdx.y. bf16, BK=64, 4 waves (2M x 2N), acc[4][6]/wave.
// ---------------------------------------------------------------------------
struct G3Args {
  const unsigned short* A;   // outp: 16384 x 2048 bf16
  const unsigned short* B;   // kernp: 192 x 2048 bf16
  float* of;                 // eparts: [2][16384][151] f32
  int kspan;                 // 1024
};

__global__ __launch_bounds__(256, 1) void gemm3w(G3Args p) {
  __shared__ __align__(16) short As[128 * 64];
  __shared__ __align__(16) short Bs[KERN_R * 64];
  const int tid  = threadIdx.x;
  const int lane = tid & 63;
  const int w    = tid >> 6;
  const int wr   = w >> 1, wc = w & 1;
  const int lr   = lane & 15;
  const int tm = blockIdx.x;
  const int kbeg = blockIdx.y * p.kspan;
  f32x4 acc[4][6] = {};

  const unsigned short* Ag = p.A + (size_t)tm * 128 * CENTP;
  const unsigned short* Bg = p.B;

  int rowa[4], cola[4], lda_[4];
#pragma unroll
  for (int i = 0; i < 4; i++) {
    int cc = i * 256 + tid;
    rowa[i] = cc >> 3;
    cola[i] = ((cc & 7) ^ (rowa[i] & 7)) * 8;
    lda_[i] = cc * 8;
  }
  int rowb[6], colbb[6], ldb_[6];
#pragma unroll
  for (int i = 0; i < 6; i++) {
    int cc = i * 256 + tid;                 // 1536 chunks = 192 rows x 8
    rowb[i] = cc >> 3;
    colbb[i] = ((cc & 7) ^ (rowb[i] & 7)) * 8;
    ldb_[i] = cc * 8;
  }

  for (int k0 = kbeg; k0 < kbeg + p.kspan; k0 += 64) {
    __syncthreads();
#pragma unroll
    for (int i = 0; i < 4; i++)
      g2l16(Ag + (size_t)rowa[i] * CENTP + k0 + cola[i], &As[lda_[i]]);
#pragma unroll
    for (int i = 0; i < 6; i++)
      g2l16(Bg + (size_t)rowb[i] * CENTP + k0 + colbb[i], &Bs[ldb_[i]]);
    __syncthreads();
#pragma unroll
    for (int ks = 0; ks < 2; ks++) {
      bf16x8 af[4], bfr[6];
#pragma unroll
      for (int m = 0; m < 4; m++) {
        int r = wr * 64 + m * 16 + lr;
        af[m] = *(const bf16x8*)&As[r * 64 + ((((ks << 2) + (lane >> 4)) ^ (r & 7)) << 3)];
      }
#pragma unroll
      for (int n = 0; n < 6; n++) {
        int r = wc * 96 + n * 16 + lr;
        bfr[n] = *(const bf16x8*)&Bs[r * 64 + ((((ks << 2) + (lane >> 4)) ^ (r & 7)) << 3)];
      }
#pragma unroll
      for (int m = 0; m < 4; m++)
#pragma unroll
        for (int n = 0; n < 6; n++)
          acc[m][n] = __builtin_amdgcn_mfma_f32_16x16x32_bf16(af[m], bfr[n], acc[m][n], 0, 0, 0);
    }
  }

  float* of = p.of + (size_t)blockIdx.y * BDIM * IN_D;
  const int rb = tm * 128 + wr * 64 + (lane >> 4) * 4;
  const int cb = wc * 96 + lr;
#pragma unroll
  for (int m = 0; m < 4; m++) {
#pragma unroll
    for (int n = 0; n < 6; n++) {
      const int gj = cb + n * 16;
#pragma unroll
      for (int r = 0; r < 4; r++) {
        const int gi = rb + m * 16 + r;
        if (gj < IN_D) of[(size_t)gi * IN_D + gj] = acc[m][n][r];
      }
    }
  }
}

// ---------------------------------------------------------------------------
// Single fused prep kernel, block-range dispatch (12273 blocks):
//   [0, 3504): cast x/cen/kern -> bf16 (+ x copy to xo output slot)
//   [3504, 8112): w1 -> fp8*8, w2 -> fp8*256
//   [8112, 12273): rownorm(x), rownorm(cen), sigmas^2
// ---------------------------------------------------------------------------
#define NB_CAST 3504
#define NB_LOWP 4608
#define NB_MISC 4161

__global__ __launch_bounds__(256) void prep_all(
    const float* __restrict__ x, const float* __restrict__ cen,
    const float* __restrict__ kern, const float* __restrict__ w1,
    const float* __restrict__ w2, const float* __restrict__ sg,
    unsigned short* __restrict__ x_bf, unsigned short* __restrict__ c_bf,
    unsigned short* __restrict__ kernp, unsigned char* __restrict__ w1p8,
    unsigned char* __restrict__ w2p8, float* __restrict__ x2,
    float* __restrict__ c2, float* __restrict__ sg2,
    float* __restrict__ xo) {
  const int b = blockIdx.x;
  if (b < NB_CAST) {
    const int c = b * 256 + threadIdx.x;
    const float* src; unsigned short* dst; int R, C, cpq, local, vec, isx;
    if (c < 786432)      { src = x;    dst = x_bf;  R = 16384; C = 151;  cpq = 48;  local = c;           vec = 0; isx = 1; }
    else if (c < 798720) { src = cen;  dst = c_bf;  R = 200;   C = 151;  cpq = 48;  local = c - 786432;  vec = 0; isx = 0; }
    else                 { src = kern; dst = kernp; R = 151;   C = 2000; cpq = 512; local = c - 798720;  vec = 1; isx = 0; }
    const int r  = local / cpq;
    const int c4 = (local - r * cpq) << 2;
    us4 o;
    if (vec && r < R && c4 + 3 < C) {
      f4 v = *(const f4*)&src[(size_t)r * C + c4];
      o[0] = f2bf(v[0]); o[1] = f2bf(v[1]); o[2] = f2bf(v[2]); o[3] = f2bf(v[3]);
    } else {
#pragma unroll
      for (int k = 0; k < 4; k++) {
        float v = (r < R && c4 + k < C) ? src[(size_t)r * C + c4 + k] : 0.f;
        o[k] = f2bf(v);
        if (isx && c4 + k < C) xo[(size_t)r * IN_D + c4 + k] = v;
      }
    }
    *(us4*)&dst[(size_t)local * 4] = o;
  } else if (b < NB_CAST + NB_LOWP) {
    const int i = (b - NB_CAST) * 256 + threadIdx.x;
    const float* src; unsigned char* dst; int r, c4, R, C; float sc;
    int j;
    if (i < 131072) { src = w1; dst = w1p8; j = i;          r = j >> 6; c4 = (j & 63) << 2;  R = 2000; C = 200;  sc = 8.f; }
    else            { src = w2; dst = w2p8; j = i - 131072; r = j >> 9; c4 = (j & 511) << 2; R = 2000; C = 2000; sc = 256.f; }
    float v[4];
#pragma unroll
    for (int k = 0; k < 4; k++)
      v[k] = (r < R && c4 + k < C) ? src[(size_t)r * C + c4 + k] * sc : 0.f;
    int p0 = __builtin_amdgcn_cvt_pk_fp8_f32(v[0], v[1], 0, false);
    int p1 = __builtin_amdgcn_cvt_pk_fp8_f32(v[2], v[3], 0, false);
    *(unsigned int*)&dst[(size_t)j * 4] =
        ((unsigned)p0 & 0xFFFFu) | (((unsigned)p1 & 0xFFFFu) << 16);
  } else {
    const int b2 = b - NB_CAST - NB_LOWP;
    if (b2 == 4160) {
      int j = threadIdx.x;
      sg2[j] = (j < HID_D) ? sg[j] * sg[j] : 0.f;
      return;
    }
    const float* src; float* dst; int R, base;
    if (b2 < 4096) { src = x;   dst = x2; R = BDIM;  base = b2 * 4; }
    else           { src = cen; dst = c2; R = HID_D; base = (b2 - 4096) * 4; }
    const int row = base + (threadIdx.x >> 6);
    const int l = threadIdx.x & 63;
    float s = 0.f;
    if (row < R)
      for (int k = l; k < IN_D; k += 64) { float v = src[(size_t)row * IN_D + k]; s += v * v; }
#pragma unroll
    for (int off = 32; off > 0; off >>= 1) s += __shfl_down(s, off);
    if (l == 0) dst[row] = s;
  }
}

// ---------------------------------------------------------------------------
// d_out layout: [Ehat2 B*151][Rhat B*2000][Ehat2 B*151][Rhat B*2000][x B*151]
// (x slot written by prep_all)
// ---------------------------------------------------------------------------
__global__ __launch_bounds__(256) void finalize(
    float* __restrict__ dout, const unsigned short* __restrict__ outp,
    const float* __restrict__ part) {
  const int i = blockIdx.x;
  const size_t SL = (size_t)BDIM * IN_D;
  float* Eh = dout;
  float* Ra = dout + SL;
  float* Eb = dout + SL + (size_t)BDIM * CENT_D;
  float* Rb = Eb + SL;
  const size_t ib = (size_t)i * IN_D;
  const float e0 = part[ib] + part[SL + ib];
  const float s = 1.f / e0;
  const int t = threadIdx.x;
  if (t < IN_D) {
    float v = (part[ib + t] + part[SL + ib + t]) * s;
    Eh[ib + t] = v;
    Eb[ib + t] = v;
  }
  if (t < 250) {
    const us8 u = *(const us8*)&outp[(size_t)i * CENTP + t * 8];
    f4 a, b;
#pragma unroll
    for (int k = 0; k < 4; k++) a[k] = bf2f(u[k]) * s;
#pragma unroll
    for (int k = 0; k < 4; k++) b[k] = bf2f(u[4 + k]) * s;
    const size_t o = (size_t)i * CENT_D + t * 8;
    *(f4*)&Ra[o] = a; *(f4*)&Ra[o + 4] = b;
    *(f4*)&Rb[o] = a; *(f4*)&Rb[o + 4] = b;
  }
}

extern "C" void kernel_launch(void* const* d_in, const int* in_sizes, int n_in,
                              void* d_out, int out_size, void* d_ws, size_t ws_size,
                              hipStream_t stream) {
  (void)in_sizes; (void)n_in; (void)out_size; (void)ws_size;
  const float* x       = (const float*)d_in[0];
  const float* centres = (const float*)d_in[1];
  const float* sigmas  = (const float*)d_in[2];
  const float* w1      = (const float*)d_in[3];
  const float* b1      = (const float*)d_in[4];
  const float* w2      = (const float*)d_in[5];
  const float* b2      = (const float*)d_in[6];
  const float* kern    = (const float*)d_in[7];
  float* dout = (float*)d_out;

  char* ws = (char*)d_ws;
  size_t off = 0;
  auto alloc = [&](size_t bytes) {
    char* p = ws + off;
    off = (off + bytes + 255) & ~(size_t)255;
    return p;
  };
  unsigned short* x_bf  = (unsigned short*)alloc((size_t)BDIM * INP * 2);
  unsigned short* c_bf  = (unsigned short*)alloc((size_t)256 * INP * 2);
  unsigned char*  w1p8  = (unsigned char*)alloc((size_t)CENTP * HIDP);
  unsigned char*  w2p8  = (unsigned char*)alloc((size_t)CENTP * CENTP);
  unsigned short* kernp = (unsigned short*)alloc((size_t)KERN_R * CENTP * 2);
  unsigned char*  phip8 = (unsigned char*)alloc((size_t)BDIM * HIDP);
  unsigned short* outp  = (unsigned short*)alloc((size_t)BDIM * CENTP * 2);
  float* x2  = (float*)alloc((size_t)BDIM * 4);
  float* c2  = (float*)alloc((size_t)256 * 4);
  float* sg2 = (float*)alloc((size_t)256 * 4);
  float* eparts = (float*)alloc((size_t)2 * BDIM * IN_D * 4);
  // h (fp8, B x 2048 = 33.5 MB) lives in the Rhat_b output slot (131 MB);
  // consumed by GEMM2, overwritten by finalize at the end.
  unsigned char* hp8 = (unsigned char*)(dout + (size_t)BDIM * (2 * IN_D + CENT_D));
  float* xo = dout + (size_t)BDIM * (2 * IN_D + 2 * CENT_D);

  prep_all<<<NB_CAST + NB_LOWP + NB_MISC, 256, 0, stream>>>(
      x, centres, kern, w1, w2, sigmas,
      x_bf, c_bf, kernp, w1p8, w2p8, x2, c2, sg2, xo);

  // GEMM0: phi -> fp8  (M=16384, N=256, K=192; 64-row tiles, 512 blocks)
  G0Args g0{}; g0.A = x_bf; g0.B = c_bf;
  g0.x2 = x2; g0.c2 = c2; g0.sg2 = sg2; g0.o8 = phip8;
  gemm_phi<<<dim3(BDIM / 64, HIDP / 128), 256, 0, stream>>>(g0);

  // GEMM1: h = relu((phi @ (8*w1)^T)/8 + b1) -> fp8  (MX-fp8, K=256)
  G8Args g1{}; g1.A = phip8; g1.B = w1p8; g1.K = HIDP;
  g1.bias = b1; g1.o8 = hp8;
  gemm_fp8<1><<<dim3(BDIM / 128, CENTP / 128), 256, 0, stream>>>(g1);

  // GEMM2: out = exp((h @ (256*w2)^T)/256 + b2) -> bf16  (MX-fp8, K=2048)
  G8Args g2{}; g2.A = hp8; g2.B = w2p8; g2.K = CENTP;
  g2.bias = b2; g2.obf = outp;
  gemm_fp8<2><<<dim3(BDIM / 128, CENTP / 128), 256, 0, stream>>>(g2);

  // GEMM3: Ehat partials (bf16, outp read once, split-K x2 -> 256 blocks)
  G3Args g3{}; g3.A = outp; g3.B = kernp; g3.of = eparts; g3.kspan = CENTP / 2;
  gemm3w<<<dim3(BDIM / 128, 2), 256, 0, stream>>>(g3);

  finalize<<<BDIM, 256, 0, stream>>>(dout, outp, eparts);
}

// Round 10
// 225.243 us; speedup vs baseline: 1.6688x; 1.0325x over previous
//
#include <hip/hip_runtime.h>

#define BDIM 16384
#define IN_D 151
#define HID_D 200
#define CENT_D 2000

#define INP 192     // K of GEMM0
#define HIDP 256    // N of GEMM0, K of GEMM1
#define CENTP 2048  // N of GEMM1/2, K of GEMM2/3
#define KERN_R 192  // kern rows padded (N of GEMM3)

using bf16x8 = __attribute__((ext_vector_type(8))) short;
using f32x4  = __attribute__((ext_vector_type(4))) float;
using f4     = __attribute__((ext_vector_type(4))) float;
using us4    = __attribute__((ext_vector_type(4))) unsigned short;
using us8    = __attribute__((ext_vector_type(8))) unsigned short;
using i32x4  = __attribute__((ext_vector_type(4))) int;
using i32x8  = __attribute__((ext_vector_type(8))) int;

__device__ __forceinline__ unsigned short f2bf(float f) {
  unsigned u = __builtin_bit_cast(unsigned, f);
  u += 0x7FFFu + ((u >> 16) & 1u);
  return (unsigned short)(u >> 16);
}
__device__ __forceinline__ float bf2f(unsigned short h) {
  unsigned u = ((unsigned)h) << 16;
  return __builtin_bit_cast(float, u);
}
__device__ __forceinline__ unsigned char f2fp8(float f) {
  return (unsigned char)(__builtin_amdgcn_cvt_pk_fp8_f32(f, f, 0, false) & 0xFF);
}

typedef __attribute__((address_space(1))) const unsigned int guint;
typedef __attribute__((address_space(3))) unsigned int luint;
__device__ __forceinline__ void g2l16(const void* g, void* l) {
  __builtin_amdgcn_global_load_lds((guint*)g, (luint*)l, 16, 0, 0);
}

// ---------------------------------------------------------------------------
// GEMM0: bf16 64x128 tile, BK=64, 4 waves (2Mx2N), 512 blocks (2/CU).
// phi -> fp8 e4m3.
// ---------------------------------------------------------------------------
struct G0Args {
  const unsigned short* A;   // x_bf: 16384 x 192 bf16
  const unsigned short* B;   // c_bf: 256 x 192 bf16
  const float* x2; const float* c2; const float* sg2;
  unsigned char* o8;         // phip8: 16384 x 256 fp8
};

__global__ __launch_bounds__(256) void gemm_phi(G0Args p) {
  __shared__ __align__(16) short As[64 * 64];
  __shared__ __align__(16) short Bs[128 * 64];
  const int tid  = threadIdx.x;
  const int lane = tid & 63;
  const int w    = tid >> 6;
  const int wr   = w >> 1, wc = w & 1;
  const int lr   = lane & 15;
  const int tm = blockIdx.x, tn = blockIdx.y;
  f32x4 acc[2][4] = {};

  const unsigned short* Ag = p.A + (size_t)tm * 64 * INP;
  const unsigned short* Bg = p.B + (size_t)tn * 128 * INP;

  int rowa[2], cola[2], lda_[2];
#pragma unroll
  for (int i = 0; i < 2; i++) {
    int cc = i * 256 + tid;          // 512 chunks = 64 rows x 8
    rowa[i] = cc >> 3;
    cola[i] = ((cc & 7) ^ (rowa[i] & 7)) * 8;
    lda_[i] = cc * 8;
  }
  int rowb[4], colb[4], ldb_[4];
#pragma unroll
  for (int i = 0; i < 4; i++) {
    int cc = i * 256 + tid;
    rowb[i] = cc >> 3;
    colb[i] = ((cc & 7) ^ (rowb[i] & 7)) * 8;
    ldb_[i] = cc * 8;
  }

  for (int k0 = 0; k0 < INP; k0 += 64) {
    __syncthreads();
#pragma unroll
    for (int i = 0; i < 2; i++)
      g2l16(Ag + (size_t)rowa[i] * INP + k0 + cola[i], &As[lda_[i]]);
#pragma unroll
    for (int i = 0; i < 4; i++)
      g2l16(Bg + (size_t)rowb[i] * INP + k0 + colb[i], &Bs[ldb_[i]]);
    __syncthreads();
#pragma unroll
    for (int ks = 0; ks < 2; ks++) {
      bf16x8 af[2], bfr[4];
#pragma unroll
      for (int m = 0; m < 2; m++) {
        int r = wr * 32 + m * 16 + lr;
        af[m] = *(const bf16x8*)&As[r * 64 + ((((ks << 2) + (lane >> 4)) ^ (r & 7)) << 3)];
      }
#pragma unroll
      for (int n = 0; n < 4; n++) {
        int r = wc * 64 + n * 16 + lr;
        bfr[n] = *(const bf16x8*)&Bs[r * 64 + ((((ks << 2) + (lane >> 4)) ^ (r & 7)) << 3)];
      }
#pragma unroll
      for (int m = 0; m < 2; m++)
#pragma unroll
        for (int n = 0; n < 4; n++)
          acc[m][n] = __builtin_amdgcn_mfma_f32_16x16x32_bf16(af[m], bfr[n], acc[m][n], 0, 0, 0);
    }
  }

  const int rb = tm * 64 + wr * 32 + (lane >> 4) * 4;
  const int cb = tn * 128 + wc * 64 + lr;
#pragma unroll
  for (int m = 0; m < 2; m++) {
#pragma unroll
    for (int n = 0; n < 4; n++) {
      const int gj = cb + n * 16;
#pragma unroll
      for (int r = 0; r < 4; r++) {
        const int gi = rb + m * 16 + r;
        float ph = 0.f;
        if (gj < HID_D) {
          float d2 = fmaxf(p.x2[gi] + p.c2[gj] - 2.f * acc[m][n][r], 0.f);
          ph = __expf(-d2 * p.sg2[gj]);
        }
        p.o8[(size_t)gi * HIDP + gj] = f2fp8(ph);
      }
    }
  }
}

// ---------------------------------------------------------------------------
// MX-fp8 128x128 tile, BK=128B, identity scales.
// Grid: 2048 LINEAR blocks with XCD-chunked swizzle (T1): XCD x owns
// tm in [x*16,(x+1)*16) across all tn -> its 4.2 MB A-stripe stays in its
// private L2 while tn sweeps (A HBM traffic 536 MB -> ~34 MB for GEMM2).
//   tm = (bx&7)*16 + ((bx>>3)&15),  tn = bx>>7   (bijective; M/128=128, N/128=16)
// MODE 1: h = relu(acc/8 + b1) -> fp8      (GEMM1: A=phi8, B=w1*8)
// MODE 2: out = exp(acc/256 + b2) -> bf16  (GEMM2: A=h8,   B=w2*256)
// ---------------------------------------------------------------------------
struct G8Args {
  const unsigned char* A;
  const unsigned char* B;
  int K;
  const float* bias;
  unsigned short* obf;       // MODE 2
  unsigned char* o8;         // MODE 1
};

template<int MODE>
__global__ __launch_bounds__(256) void gemm_fp8(G8Args p) {
  __shared__ __align__(16) unsigned char As[128 * 128];
  __shared__ __align__(16) unsigned char Bs[128 * 128];
  const int tid  = threadIdx.x;
  const int lane = tid & 63;
  const int w    = tid >> 6;
  const int wr   = w >> 1, wc = w & 1;
  const int lr   = lane & 15;
  const int g    = lane >> 4;
  const int bx   = blockIdx.x;
  const int tm   = ((bx & 7) << 4) | ((bx >> 3) & 15);
  const int tn   = bx >> 7;
  const int K = p.K;
  f32x4 acc[4][4] = {};

  const unsigned char* Ag = p.A + (size_t)tm * 128 * K;
  const unsigned char* Bg = p.B + (size_t)tn * 128 * K;

  int rowc[4], colb[4], ldsb[4];
#pragma unroll
  for (int i = 0; i < 4; i++) {
    int cc = i * 256 + tid;
    rowc[i] = cc >> 3;
    colb[i] = ((cc & 7) ^ (rowc[i] & 7)) << 4;
    ldsb[i] = cc << 4;
  }

  for (int k0 = 0; k0 < K; k0 += 128) {
    __syncthreads();
#pragma unroll
    for (int i = 0; i < 4; i++)
      g2l16(Ag + (size_t)rowc[i] * K + k0 + colb[i], &As[ldsb[i]]);
#pragma unroll
    for (int i = 0; i < 4; i++)
      g2l16(Bg + (size_t)rowc[i] * K + k0 + colb[i], &Bs[ldsb[i]]);
    __syncthreads();

    i32x8 bfr[4];
#pragma unroll
    for (int n = 0; n < 4; n++) {
      const int r = wc * 64 + n * 16 + lr;
      const int rb_ = r << 7, rx = r & 7;
      i32x4 lo = *(const i32x4*)&Bs[rb_ + (((2 * g) ^ rx) << 4)];
      i32x4 hi = *(const i32x4*)&Bs[rb_ + (((2 * g + 1) ^ rx) << 4)];
      bfr[n][0] = lo[0]; bfr[n][1] = lo[1]; bfr[n][2] = lo[2]; bfr[n][3] = lo[3];
      bfr[n][4] = hi[0]; bfr[n][5] = hi[1]; bfr[n][6] = hi[2]; bfr[n][7] = hi[3];
    }
#pragma unroll
    for (int m = 0; m < 4; m++) {
      const int r = wr * 64 + m * 16 + lr;
      const int rb_ = r << 7, rx = r & 7;
      i32x4 lo = *(const i32x4*)&As[rb_ + (((2 * g) ^ rx) << 4)];
      i32x4 hi = *(const i32x4*)&As[rb_ + (((2 * g + 1) ^ rx) << 4)];
      i32x8 av;
      av[0] = lo[0]; av[1] = lo[1]; av[2] = lo[2]; av[3] = lo[3];
      av[4] = hi[0]; av[5] = hi[1]; av[6] = hi[2]; av[7] = hi[3];
#pragma unroll
      for (int n = 0; n < 4; n++)
        acc[m][n] = __builtin_amdgcn_mfma_scale_f32_16x16x128_f8f6f4(
            av, bfr[n], acc[m][n], 0, 0, 0, 127, 0, 127);
    }
  }

  const int rb = tm * 128 + wr * 64 + (lane >> 4) * 4;
  const int cb = tn * 128 + wc * 64 + lr;
  const float rs = (MODE == 1) ? 0.125f : (1.0f / 256.0f);
#pragma unroll
  for (int m = 0; m < 4; m++) {
#pragma unroll
    for (int n = 0; n < 4; n++) {
      const int gj = cb + n * 16;
      const float b = (gj < CENT_D) ? p.bias[gj] : 0.f;
#pragma unroll
      for (int r = 0; r < 4; r++) {
        const int gi = rb + m * 16 + r;
        if constexpr (MODE == 1) {
          p.o8[(size_t)gi * CENTP + gj] = f2fp8(fmaxf(acc[m][n][r] * rs + b, 0.f));
        } else {
          float o = (gj < CENT_D) ? __expf(acc[m][n][r] * rs + b) : 0.f;
          p.obf[(size_t)gi * CENTP + gj] = f2bf(o);
        }
      }
    }
  }
}

// ---------------------------------------------------------------------------
// GEMM3: Ehat partials. BN=192 held per block (outp read ONCE), split-K x2
// via blockIdx.y. bf16, BK=64, 4 waves (2M x 2N), acc[4][6]/wave.
// ---------------------------------------------------------------------------
struct G3Args {
  const unsigned short* A;   // outp: 16384 x 2048 bf16
  const unsigned short* B;   // kernp: 192 x 2048 bf16
  float* of;                 // eparts: [2][16384][151] f32
  int kspan;                 // 1024
};

__global__ __launch_bounds__(256, 1) void gemm3w(G3Args p) {
  __shared__ __align__(16) short As[128 * 64];
  __shared__ __align__(16) short Bs[KERN_R * 64];
  const int tid  = threadIdx.x;
  const int lane = tid & 63;
  const int w    = tid >> 6;
  const int wr   = w >> 1, wc = w & 1;
  const int lr   = lane & 15;
  const int tm = blockIdx.x;
  const int kbeg = blockIdx.y * p.kspan;
  f32x4 acc[4][6] = {};

  const unsigned short* Ag = p.A + (size_t)tm * 128 * CENTP;
  const unsigned short* Bg = p.B;

  int rowa[4], cola[4], lda_[4];
#pragma unroll
  for (int i = 0; i < 4; i++) {
    int cc = i * 256 + tid;
    rowa[i] = cc >> 3;
    cola[i] = ((cc & 7) ^ (rowa[i] & 7)) * 8;
    lda_[i] = cc * 8;
  }
  int rowb[6], colbb[6], ldb_[6];
#pragma unroll
  for (int i = 0; i < 6; i++) {
    int cc = i * 256 + tid;                 // 1536 chunks = 192 rows x 8
    rowb[i] = cc >> 3;
    colbb[i] = ((cc & 7) ^ (rowb[i] & 7)) * 8;
    ldb_[i] = cc * 8;
  }

  for (int k0 = kbeg; k0 < kbeg + p.kspan; k0 += 64) {
    __syncthreads();
#pragma unroll
    for (int i = 0; i < 4; i++)
      g2l16(Ag + (size_t)rowa[i] * CENTP + k0 + cola[i], &As[lda_[i]]);
#pragma unroll
    for (int i = 0; i < 6; i++)
      g2l16(Bg + (size_t)rowb[i] * CENTP + k0 + colbb[i], &Bs[ldb_[i]]);
    __syncthreads();
#pragma unroll
    for (int ks = 0; ks < 2; ks++) {
      bf16x8 af[4], bfr[6];
#pragma unroll
      for (int m = 0; m < 4; m++) {
        int r = wr * 64 + m * 16 + lr;
        af[m] = *(const bf16x8*)&As[r * 64 + ((((ks << 2) + (lane >> 4)) ^ (r & 7)) << 3)];
      }
#pragma unroll
      for (int n = 0; n < 6; n++) {
        int r = wc * 96 + n * 16 + lr;
        bfr[n] = *(const bf16x8*)&Bs[r * 64 + ((((ks << 2) + (lane >> 4)) ^ (r & 7)) << 3)];
      }
#pragma unroll
      for (int m = 0; m < 4; m++)
#pragma unroll
        for (int n = 0; n < 6; n++)
          acc[m][n] = __builtin_amdgcn_mfma_f32_16x16x32_bf16(af[m], bfr[n], acc[m][n], 0, 0, 0);
    }
  }

  float* of = p.of + (size_t)blockIdx.y * BDIM * IN_D;
  const int rb = tm * 128 + wr * 64 + (lane >> 4) * 4;
  const int cb = wc * 96 + lr;
#pragma unroll
  for (int m = 0; m < 4; m++) {
#pragma unroll
    for (int n = 0; n < 6; n++) {
      const int gj = cb + n * 16;
#pragma unroll
      for (int r = 0; r < 4; r++) {
        const int gi = rb + m * 16 + r;
        if (gj < IN_D) of[(size_t)gi * IN_D + gj] = acc[m][n][r];
      }
    }
  }
}

// ---------------------------------------------------------------------------
// Single fused prep kernel, block-range dispatch (12273 blocks):
//   [0, 3504): cast x/cen/kern -> bf16 (+ x copy to xo output slot)
//   [3504, 8112): w1 -> fp8*8, w2 -> fp8*256
//   [8112, 12273): rownorm(x), rownorm(cen), sigmas^2
// ---------------------------------------------------------------------------
#define NB_CAST 3504
#define NB_LOWP 4608
#define NB_MISC 4161

__global__ __launch_bounds__(256) void prep_all(
    const float* __restrict__ x, const float* __restrict__ cen,
    const float* __restrict__ kern, const float* __restrict__ w1,
    const float* __restrict__ w2, const float* __restrict__ sg,
    unsigned short* __restrict__ x_bf, unsigned short* __restrict__ c_bf,
    unsigned short* __restrict__ kernp, unsigned char* __restrict__ w1p8,
    unsigned char* __restrict__ w2p8, float* __restrict__ x2,
    float* __restrict__ c2, float* __restrict__ sg2,
    float* __restrict__ xo) {
  const int b = blockIdx.x;
  if (b < NB_CAST) {
    const int c = b * 256 + threadIdx.x;
    const float* src; unsigned short* dst; int R, C, cpq, local, vec, isx;
    if (c < 786432)      { src = x;    dst = x_bf;  R = 16384; C = 151;  cpq = 48;  local = c;           vec = 0; isx = 1; }
    else if (c < 798720) { src = cen;  dst = c_bf;  R = 200;   C = 151;  cpq = 48;  local = c - 786432;  vec = 0; isx = 0; }
    else                 { src = kern; dst = kernp; R = 151;   C = 2000; cpq = 512; local = c - 798720;  vec = 1; isx = 0; }
    const int r  = local / cpq;
    const int c4 = (local - r * cpq) << 2;
    us4 o;
    if (vec && r < R && c4 + 3 < C) {
      f4 v = *(const f4*)&src[(size_t)r * C + c4];
      o[0] = f2bf(v[0]); o[1] = f2bf(v[1]); o[2] = f2bf(v[2]); o[3] = f2bf(v[3]);
    } else {
#pragma unroll
      for (int k = 0; k < 4; k++) {
        float v = (r < R && c4 + k < C) ? src[(size_t)r * C + c4 + k] : 0.f;
        o[k] = f2bf(v);
        if (isx && c4 + k < C) xo[(size_t)r * IN_D + c4 + k] = v;
      }
    }
    *(us4*)&dst[(size_t)local * 4] = o;
  } else if (b < NB_CAST + NB_LOWP) {
    const int i = (b - NB_CAST) * 256 + threadIdx.x;
    const float* src; unsigned char* dst; int r, c4, R, C; float sc;
    int j;
    if (i < 131072) { src = w1; dst = w1p8; j = i;          r = j >> 6; c4 = (j & 63) << 2;  R = 2000; C = 200;  sc = 8.f; }
    else            { src = w2; dst = w2p8; j = i - 131072; r = j >> 9; c4 = (j & 511) << 2; R = 2000; C = 2000; sc = 256.f; }
    float v[4];
#pragma unroll
    for (int k = 0; k < 4; k++)
      v[k] = (r < R && c4 + k < C) ? src[(size_t)r * C + c4 + k] * sc : 0.f;
    int p0 = __builtin_amdgcn_cvt_pk_fp8_f32(v[0], v[1], 0, false);
    int p1 = __builtin_amdgcn_cvt_pk_fp8_f32(v[2], v[3], 0, false);
    *(unsigned int*)&dst[(size_t)j * 4] =
        ((unsigned)p0 & 0xFFFFu) | (((unsigned)p1 & 0xFFFFu) << 16);
  } else {
    const int b2 = b - NB_CAST - NB_LOWP;
    if (b2 == 4160) {
      int j = threadIdx.x;
      sg2[j] = (j < HID_D) ? sg[j] * sg[j] : 0.f;
      return;
    }
    const float* src; float* dst; int R, base;
    if (b2 < 4096) { src = x;   dst = x2; R = BDIM;  base = b2 * 4; }
    else           { src = cen; dst = c2; R = HID_D; base = (b2 - 4096) * 4; }
    const int row = base + (threadIdx.x >> 6);
    const int l = threadIdx.x & 63;
    float s = 0.f;
    if (row < R)
      for (int k = l; k < IN_D; k += 64) { float v = src[(size_t)row * IN_D + k]; s += v * v; }
#pragma unroll
    for (int off = 32; off > 0; off >>= 1) s += __shfl_down(s, off);
    if (l == 0) dst[row] = s;
  }
}

// ---------------------------------------------------------------------------
// d_out layout: [Ehat2 B*151][Rhat B*2000][Ehat2 B*151][Rhat B*2000][x B*151]
// (x slot written by prep_all)
// ---------------------------------------------------------------------------
__global__ __launch_bounds__(256) void finalize(
    float* __restrict__ dout, const unsigned short* __restrict__ outp,
    const float* __restrict__ part) {
  const int i = blockIdx.x;
  const size_t SL = (size_t)BDIM * IN_D;
  float* Eh = dout;
  float* Ra = dout + SL;
  float* Eb = dout + SL + (size_t)BDIM * CENT_D;
  float* Rb = Eb + SL;
  const size_t ib = (size_t)i * IN_D;
  const float e0 = part[ib] + part[SL + ib];
  const float s = 1.f / e0;
  const int t = threadIdx.x;
  if (t < IN_D) {
    float v = (part[ib + t] + part[SL + ib + t]) * s;
    Eh[ib + t] = v;
    Eb[ib + t] = v;
  }
  if (t < 250) {
    const us8 u = *(const us8*)&outp[(size_t)i * CENTP + t * 8];
    f4 a, b;
#pragma unroll
    for (int k = 0; k < 4; k++) a[k] = bf2f(u[k]) * s;
#pragma unroll
    for (int k = 0; k < 4; k++) b[k] = bf2f(u[4 + k]) * s;
    const size_t o = (size_t)i * CENT_D + t * 8;
    *(f4*)&Ra[o] = a; *(f4*)&Ra[o + 4] = b;
    *(f4*)&Rb[o] = a; *(f4*)&Rb[o + 4] = b;
  }
}

extern "C" void kernel_launch(void* const* d_in, const int* in_sizes, int n_in,
                              void* d_out, int out_size, void* d_ws, size_t ws_size,
                              hipStream_t stream) {
  (void)in_sizes; (void)n_in; (void)out_size; (void)ws_size;
  const float* x       = (const float*)d_in[0];
  const float* centres = (const float*)d_in[1];
  const float* sigmas  = (const float*)d_in[2];
  const float* w1      = (const float*)d_in[3];
  const float* b1      = (const float*)d_in[4];
  const float* w2      = (const float*)d_in[5];
  const float* b2      = (const float*)d_in[6];
  const float* kern    = (const float*)d_in[7];
  float* dout = (float*)d_out;

  char* ws = (char*)d_ws;
  size_t off = 0;
  auto alloc = [&](size_t bytes) {
    char* p = ws + off;
    off = (off + bytes + 255) & ~(size_t)255;
    return p;
  };
  unsigned short* x_bf  = (unsigned short*)alloc((size_t)BDIM * INP * 2);
  unsigned short* c_bf  = (unsigned short*)alloc((size_t)256 * INP * 2);
  unsigned char*  w1p8  = (unsigned char*)alloc((size_t)CENTP * HIDP);
  unsigned char*  w2p8  = (unsigned char*)alloc((size_t)CENTP * CENTP);
  unsigned short* kernp = (unsigned short*)alloc((size_t)KERN_R * CENTP * 2);
  unsigned char*  phip8 = (unsigned char*)alloc((size_t)BDIM * HIDP);
  unsigned short* outp  = (unsigned short*)alloc((size_t)BDIM * CENTP * 2);
  float* x2  = (float*)alloc((size_t)BDIM * 4);
  float* c2  = (float*)alloc((size_t)256 * 4);
  float* sg2 = (float*)alloc((size_t)256 * 4);
  float* eparts = (float*)alloc((size_t)2 * BDIM * IN_D * 4);
  // h (fp8, B x 2048 = 33.5 MB) lives in the Rhat_b output slot (131 MB);
  // consumed by GEMM2, overwritten by finalize at the end.
  unsigned char* hp8 = (unsigned char*)(dout + (size_t)BDIM * (2 * IN_D + CENT_D));
  float* xo = dout + (size_t)BDIM * (2 * IN_D + 2 * CENT_D);

  prep_all<<<NB_CAST + NB_LOWP + NB_MISC, 256, 0, stream>>>(
      x, centres, kern, w1, w2, sigmas,
      x_bf, c_bf, kernp, w1p8, w2p8, x2, c2, sg2, xo);

  // GEMM0: phi -> fp8  (M=16384, N=256, K=192; 64-row tiles, 512 blocks)
  G0Args g0{}; g0.A = x_bf; g0.B = c_bf;
  g0.x2 = x2; g0.c2 = c2; g0.sg2 = sg2; g0.o8 = phip8;
  gemm_phi<<<dim3(BDIM / 64, HIDP / 128), 256, 0, stream>>>(g0);

  // GEMM1: h = relu((phi @ (8*w1)^T)/8 + b1) -> fp8  (MX-fp8, K=256, XCD-swz)
  G8Args g1{}; g1.A = phip8; g1.B = w1p8; g1.K = HIDP;
  g1.bias = b1; g1.o8 = hp8;
  gemm_fp8<1><<<2048, 256, 0, stream>>>(g1);

  // GEMM2: out = exp((h @ (256*w2)^T)/256 + b2) -> bf16  (MX-fp8, K=2048, XCD-swz)
  G8Args g2{}; g2.A = hp8; g2.B = w2p8; g2.K = CENTP;
  g2.bias = b2; g2.obf = outp;
  gemm_fp8<2><<<2048, 256, 0, stream>>>(g2);

  // GEMM3: Ehat partials (bf16, outp read once, split-K x2 -> 256 blocks)
  G3Args g3{}; g3.A = outp; g3.B = kernp; g3.of = eparts; g3.kspan = CENTP / 2;
  gemm3w<<<dim3(BDIM / 128, 2), 256, 0, stream>>>(g3);

  finalize<<<BDIM, 256, 0, stream>>>(dout, outp, eparts);
}